// Round 2
// baseline (594.435 us; speedup 1.0000x reference)
//
#include <hip/hip_runtime.h>

#define NN 50000
#define NE 600000
#define DD 128
#define XS 264   // padded LDS row stride in bf16 elems: 528 B = 33*16 (16B aligned), %32-dword offset 4 -> 2-way bank alias (free)
#define EW 6250  // k_edges wave count (1-wave blocks); each wave does 3 tiles of 32 edges: 6250*3*32 = NE

typedef unsigned short u16;
typedef u16   u16x8  __attribute__((ext_vector_type(8)));
typedef u16   u16x4  __attribute__((ext_vector_type(4)));
typedef __bf16 bf16x8 __attribute__((ext_vector_type(8)));
typedef float f32x4  __attribute__((ext_vector_type(4)));

__device__ __forceinline__ u16 f2bf(float f) {  // RNE fp32->bf16
    unsigned u = __builtin_bit_cast(unsigned, f);
    u += 0x7FFFu + ((u >> 16) & 1u);
    return (u16)(u >> 16);
}

// node_features fp32 [NN,DD] -> bf16 table
__global__ void k_convert_nf(const float* __restrict__ nf, u16* __restrict__ out) {
    int id = blockIdx.x * 256 + threadIdx.x;            // NN*DD/4 threads exactly
    float4 v = ((const float4*)nf)[id];
    u16x4 o; o[0] = f2bf(v.x); o[1] = f2bf(v.y); o[2] = f2bf(v.z); o[3] = f2bf(v.w);
    ((u16x4*)out)[id] = o;
}

// Pack W[K,N] fp32 row-major into MFMA B-fragment order for 16x16x32:
// frag = nt*KT + kt (KT = K/32); within frag: lane*8 + j holds
// W[kt*32 + (lane>>4)*8 + j][nt*16 + (lane&15)]
__global__ void k_pack(const float* __restrict__ W, u16* __restrict__ out, int K, int N) {
    int tid = blockIdx.x * 256 + threadIdx.x;
    if (tid >= K * N) return;
    int frag = tid >> 9, lane = (tid >> 3) & 63, j = tid & 7;
    int KT = K >> 5;
    int nt = frag / KT, kt = frag - nt * KT;
    int row = kt * 32 + ((lane >> 4) << 3) + j;
    int col = nt * 16 + (lane & 15);
    out[tid] = f2bf(W[row * N + col]);
}

// ---------------- edge kernel: 1 wave/block, barrier-free, software-pipelined ----------------
// A-frag for 16x16x32: lane (quad,l15), elem j = X[mt*16+l15][kt*32+quad*8+j].
// X row = [from_feat(128) | to_feat(128)]  =>  frag is 16 contiguous bytes of a node row:
//   kt<4 : nf16[from*128 + kt*32 + quad*8],  kt>=4 : nf16[to*128 + (kt-4)*32 + quad*8]
// so A-frags gather straight from global; no X staging, no barrier. LDS holds only H (wave-private).

__device__ __forceinline__ void load_eidx(const int* __restrict__ from_idx,
                                          const int* __restrict__ to_idx,
                                          int e0, int l15, int (&fm)[2], int (&tn)[2]) {
    #pragma unroll
    for (int mt = 0; mt < 2; ++mt) {
        int e = e0 + mt * 16 + l15;
        fm[mt] = from_idx[e];
        tn[mt] = to_idx[e];
    }
}

__device__ __forceinline__ void gather_frags(bf16x8 (&a)[2][8], const u16* __restrict__ nf16,
                                             const int (&fm)[2], const int (&tn)[2], int q8) {
    #pragma unroll
    for (int mt = 0; mt < 2; ++mt) {
        const u16* rf = nf16 + (size_t)fm[mt] * DD + q8;
        const u16* rt = nf16 + (size_t)tn[mt] * DD + q8;
        #pragma unroll
        for (int kt = 0; kt < 4; ++kt) {
            a[mt][kt]     = __builtin_bit_cast(bf16x8, *(const u16x8*)(rf + kt * 32));
            a[mt][kt + 4] = __builtin_bit_cast(bf16x8, *(const u16x8*)(rt + kt * 32));
        }
    }
}

__device__ __forceinline__ void compute_tile(bf16x8 (&a)[2][8], u16* __restrict__ sH,
        const int* __restrict__ to_idx, const u16* __restrict__ pW0,
        const float* __restrict__ b0, const u16* __restrict__ pW1,
        const float* __restrict__ b1, float* __restrict__ agg,
        int e0, int lane, int l15, int quad) {
    // scatter indices: issue early, consumed only after layer 0 (latency hidden under MFMA)
    int tI[2][4];
    #pragma unroll
    for (int mt = 0; mt < 2; ++mt) {
        #pragma unroll
        for (int i = 0; i < 4; ++i)
            tI[mt][i] = to_idx[e0 + mt * 16 + quad * 4 + i];
    }

    // layer 0: H[32,256] = relu(X @ W0 + b0), H kept in wave-private LDS
    for (int nt = 0; nt < 16; ++nt) {
        f32x4 c0 = {0.f, 0.f, 0.f, 0.f}, c1 = {0.f, 0.f, 0.f, 0.f};
        #pragma unroll
        for (int kt = 0; kt < 8; ++kt) {
            bf16x8 b = __builtin_bit_cast(bf16x8, *(const u16x8*)(pW0 + (nt * 8 + kt) * 512 + lane * 8));
            c0 = __builtin_amdgcn_mfma_f32_16x16x32_bf16(a[0][kt], b, c0, 0, 0, 0);
            c1 = __builtin_amdgcn_mfma_f32_16x16x32_bf16(a[1][kt], b, c1, 0, 0, 0);
        }
        float bias = b0[nt * 16 + l15];
        #pragma unroll
        for (int i = 0; i < 4; ++i) {
            sH[(quad * 4 + i) * XS + nt * 16 + l15]      = f2bf(fmaxf(c0[i] + bias, 0.f));
            sH[(16 + quad * 4 + i) * XS + nt * 16 + l15] = f2bf(fmaxf(c1[i] + bias, 0.f));
        }
    }

    // layer-1 A-frags from H (same wave wrote them; in-order DS pipe, no barrier). Reuses a[].
    #pragma unroll
    for (int mt = 0; mt < 2; ++mt) {
        #pragma unroll
        for (int kt = 0; kt < 8; ++kt)
            a[mt][kt] = __builtin_bit_cast(bf16x8, *(const u16x8*)(&sH[(mt * 16 + l15) * XS + kt * 32 + quad * 8]));
    }

    // layer 1: m = relu(H @ W1 + b1), scatter-add into agg (fire-and-forget atomics)
    for (int nt = 0; nt < 8; ++nt) {
        f32x4 c0 = {0.f, 0.f, 0.f, 0.f}, c1 = {0.f, 0.f, 0.f, 0.f};
        #pragma unroll
        for (int kt = 0; kt < 8; ++kt) {
            bf16x8 b = __builtin_bit_cast(bf16x8, *(const u16x8*)(pW1 + (nt * 8 + kt) * 512 + lane * 8));
            c0 = __builtin_amdgcn_mfma_f32_16x16x32_bf16(a[0][kt], b, c0, 0, 0, 0);
            c1 = __builtin_amdgcn_mfma_f32_16x16x32_bf16(a[1][kt], b, c1, 0, 0, 0);
        }
        float bias = b1[nt * 16 + l15];
        int col = nt * 16 + l15;
        #pragma unroll
        for (int i = 0; i < 4; ++i) {
            unsafeAtomicAdd(&agg[(size_t)tI[0][i] * DD + col], fmaxf(c0[i] + bias, 0.f));
            unsafeAtomicAdd(&agg[(size_t)tI[1][i] * DD + col], fmaxf(c1[i] + bias, 0.f));
        }
    }
}

__global__ __launch_bounds__(64, 3) void k_edges(
    const u16* __restrict__ nf16, const int* __restrict__ from_idx,
    const int* __restrict__ to_idx, const u16* __restrict__ pW0,
    const float* __restrict__ b0, const u16* __restrict__ pW1,
    const float* __restrict__ b1, float* __restrict__ agg)
{
    __shared__ u16 sH[32 * XS];   // 16,896 B: H only, wave-private -> 9 blocks/CU
    const int lane = threadIdx.x; // 64 threads = 1 wave
    const int l15  = lane & 15;
    const int quad = lane >> 4;
    const int q8   = quad * 8;
    const int e0 = blockIdx.x * 32;
    const int e1 = e0 + EW * 32;
    const int e2 = e1 + EW * 32;

    int fiA[2], tiA[2], fiB[2], tiB[2];
    bf16x8 A[2][8], B[2][8];

    // prologue: indices for tiles 0,1 then both gathers in flight
    load_eidx(from_idx, to_idx, e0, l15, fiA, tiA);
    load_eidx(from_idx, to_idx, e1, l15, fiB, tiB);
    gather_frags(A, nf16, fiA, tiA, q8);
    gather_frags(B, nf16, fiB, tiB, q8);
    load_eidx(from_idx, to_idx, e2, l15, fiA, tiA);      // tile-2 indices (idx regs reusable)

    compute_tile(A, sH, to_idx, pW0, b0, pW1, b1, agg, e0, lane, l15, quad);
    gather_frags(A, nf16, fiA, tiA, q8);                 // tile-2 gather overlaps tile-1 compute
    compute_tile(B, sH, to_idx, pW0, b0, pW1, b1, agg, e1, lane, l15, quad);
    compute_tile(A, sH, to_idx, pW0, b0, pW1, b1, agg, e2, lane, l15, quad);
}

// Node update: out = nf + relu(relu([agg|nf] @ uW0 + ub0) @ uW1 + ub1)   (unchanged this round)
__global__ __launch_bounds__(128) void k_update(
    const float* __restrict__ agg, const u16* __restrict__ nf16,
    const float* __restrict__ nf32, const u16* __restrict__ pW0,
    const float* __restrict__ b0, const u16* __restrict__ pW1,
    const float* __restrict__ b1, float* __restrict__ out)
{
    __shared__ u16 sX[64 * XS];
    const int tid = threadIdx.x;
    const int n0 = blockIdx.x * 64;

    // stage agg half (cols 0..127), fp32->bf16
    #pragma unroll
    for (int i = 0; i < 16; ++i) {
        int c = i * 128 + tid;
        int r = c >> 5, j = c & 31;
        int n = n0 + r;
        u16x4 o;
        if (n < NN) {
            float4 v = *(const float4*)(agg + (size_t)n * DD + j * 4);
            o[0] = f2bf(v.x); o[1] = f2bf(v.y); o[2] = f2bf(v.z); o[3] = f2bf(v.w);
        } else { o[0] = 0; o[1] = 0; o[2] = 0; o[3] = 0; }
        *(u16x4*)(&sX[r * XS + j * 4]) = o;
    }
    // stage nf half (cols 128..255), bf16 copy
    #pragma unroll
    for (int i = 0; i < 8; ++i) {
        int c = i * 128 + tid;
        int r = c >> 4, j = c & 15;
        int n = n0 + r;
        u16x8 v = {0, 0, 0, 0, 0, 0, 0, 0};
        if (n < NN) v = *(const u16x8*)(nf16 + (size_t)n * DD + j * 8);
        *(u16x8*)(&sX[r * XS + 128 + j * 8]) = v;
    }
    __syncthreads();

    const int lane = tid & 63;
    const int wave = tid >> 6;
    const int base = wave * 32;
    const int l15  = lane & 15;
    const int quad = lane >> 4;
    const int arow0 = (base + l15) * XS + quad * 8;

    bf16x8 a[2][8];
    #pragma unroll
    for (int mt = 0; mt < 2; ++mt)
        #pragma unroll
        for (int kt = 0; kt < 8; ++kt)
            a[mt][kt] = __builtin_bit_cast(bf16x8, *(const u16x8*)(&sX[arow0 + mt * 16 * XS + kt * 32]));

    for (int nt = 0; nt < 16; ++nt) {
        f32x4 c0 = {0.f, 0.f, 0.f, 0.f}, c1 = {0.f, 0.f, 0.f, 0.f};
        #pragma unroll
        for (int kt = 0; kt < 8; ++kt) {
            bf16x8 b = __builtin_bit_cast(bf16x8, *(const u16x8*)(pW0 + (nt * 8 + kt) * 512 + lane * 8));
            c0 = __builtin_amdgcn_mfma_f32_16x16x32_bf16(a[0][kt], b, c0, 0, 0, 0);
            c1 = __builtin_amdgcn_mfma_f32_16x16x32_bf16(a[1][kt], b, c1, 0, 0, 0);
        }
        float bias = b0[nt * 16 + l15];
        #pragma unroll
        for (int i = 0; i < 4; ++i) {
            sX[(base +      quad * 4 + i) * XS + nt * 16 + l15] = f2bf(fmaxf(c0[i] + bias, 0.f));
            sX[(base + 16 + quad * 4 + i) * XS + nt * 16 + l15] = f2bf(fmaxf(c1[i] + bias, 0.f));
        }
    }

    #pragma unroll
    for (int mt = 0; mt < 2; ++mt)
        #pragma unroll
        for (int kt = 0; kt < 8; ++kt)
            a[mt][kt] = __builtin_bit_cast(bf16x8, *(const u16x8*)(&sX[arow0 + mt * 16 * XS + kt * 32]));

    for (int nt = 0; nt < 8; ++nt) {
        f32x4 c0 = {0.f, 0.f, 0.f, 0.f}, c1 = {0.f, 0.f, 0.f, 0.f};
        #pragma unroll
        for (int kt = 0; kt < 8; ++kt) {
            bf16x8 b = __builtin_bit_cast(bf16x8, *(const u16x8*)(pW1 + (nt * 8 + kt) * 512 + lane * 8));
            c0 = __builtin_amdgcn_mfma_f32_16x16x32_bf16(a[0][kt], b, c0, 0, 0, 0);
            c1 = __builtin_amdgcn_mfma_f32_16x16x32_bf16(a[1][kt], b, c1, 0, 0, 0);
        }
        float bias = b1[nt * 16 + l15];
        int col = nt * 16 + l15;
        #pragma unroll
        for (int i = 0; i < 4; ++i) {
            int na = n0 + base +      quad * 4 + i;
            int nb = n0 + base + 16 + quad * 4 + i;
            if (na < NN) out[(size_t)na * DD + col] = nf32[(size_t)na * DD + col] + fmaxf(c0[i] + bias, 0.f);
            if (nb < NN) out[(size_t)nb * DD + col] = nf32[(size_t)nb * DD + col] + fmaxf(c1[i] + bias, 0.f);
        }
    }
}

extern "C" void kernel_launch(void* const* d_in, const int* in_sizes, int n_in,
                              void* d_out, int out_size, void* d_ws, size_t ws_size,
                              hipStream_t stream)
{
    const float* nf  = (const float*)d_in[0];
    const int* fidx  = (const int*)d_in[1];
    const int* tidx  = (const int*)d_in[2];
    const float* mW0 = (const float*)d_in[3];
    const float* mb0 = (const float*)d_in[4];
    const float* mW1 = (const float*)d_in[5];
    const float* mb1 = (const float*)d_in[6];
    const float* uW0 = (const float*)d_in[7];
    const float* ub0 = (const float*)d_in[8];
    const float* uW1 = (const float*)d_in[9];
    const float* ub1 = (const float*)d_in[10];
    float* out = (float*)d_out;

    char* ws = (char*)d_ws;
    u16*   nf16 = (u16*)ws;   ws += (size_t)NN * DD * 2;   // 12.8 MB
    float* agg  = (float*)ws; ws += (size_t)NN * DD * 4;   // 25.6 MB
    u16*   pmW0 = (u16*)ws;   ws += 256 * 256 * 2;
    u16*   pmW1 = (u16*)ws;   ws += 256 * 128 * 2;
    u16*   puW0 = (u16*)ws;   ws += 256 * 256 * 2;
    u16*   puW1 = (u16*)ws;   ws += 256 * 128 * 2;

    hipMemsetAsync(agg, 0, (size_t)NN * DD * 4, stream);
    k_convert_nf<<<(NN * DD / 4) / 256, 256, 0, stream>>>(nf, nf16);
    k_pack<<<256, 256, 0, stream>>>(mW0, pmW0, 256, 256);
    k_pack<<<128, 256, 0, stream>>>(mW1, pmW1, 256, 128);
    k_pack<<<256, 256, 0, stream>>>(uW0, puW0, 256, 256);
    k_pack<<<128, 256, 0, stream>>>(uW1, puW1, 256, 128);
    k_edges<<<EW, 64, 0, stream>>>(nf16, fidx, tidx, pmW0, mb0, pmW1, mb1, agg);
    k_update<<<(NN + 63) / 64, 128, 0, stream>>>(agg, nf16, nf, puW0, ub0, puW1, ub1, out);
}